// Round 17
// baseline (550.355 us; speedup 1.0000x reference)
//
#include <hip/hip_runtime.h>

typedef unsigned short u16;
typedef float f32x4 __attribute__((ext_vector_type(4)));
typedef __bf16 bf16x8 __attribute__((ext_vector_type(8)));

#define DEV static __device__ __forceinline__

DEV u16 f2bf(float f) {
  union { float f; unsigned u; } c; c.f = f;
  unsigned u = c.u;
  u += 0x7fffu + ((u >> 16) & 1u);   // RNE; inputs are normal floats
  return (u16)(u >> 16);
}
DEV float bf2f(u16 h) {
  union { float f; unsigned u; } c; c.u = ((unsigned)h) << 16;
  return c.f;
}
DEV f32x4 MFMA(bf16x8 a, bf16x8 b, f32x4 c) {
  return __builtin_amdgcn_mfma_f32_16x16x32_bf16(a, b, c, 0, 0, 0);
}
DEV unsigned cvt_pk_bf16(float a, float b) {   // low16 = a, high16 = b (RNE)
  unsigned r;
  asm("v_cvt_pk_bf16_f32 %0, %1, %2" : "=v"(r) : "v"(a), "v"(b));
  return r;
}
DEV float ex2(float x) { return __builtin_amdgcn_exp2f(x); }
DEV void glds16(const void* src, void* lds) {   // async global->LDS, 16B/lane
  __builtin_amdgcn_global_load_lds(
      (__attribute__((address_space(1))) void*)src,
      (__attribute__((address_space(3))) void*)lds, 16, 0, 0);
}
DEV void barrier_raw() {                        // raw s_barrier: NO vmcnt drain
  __builtin_amdgcn_sched_barrier(0);
  asm volatile("s_barrier" ::: "memory");
  __builtin_amdgcn_sched_barrier(0);
}
#define VMCNT(N)                                              \
  do {                                                        \
    asm volatile("s_waitcnt vmcnt(" #N ")" ::: "memory");     \
    __builtin_amdgcn_sched_barrier(0);                        \
  } while (0)

// ---------------- constants ----------------
// B=2 L=2048 DM=2048 H=16 KV=4 GROUP=4 DK=128 DV=512
// qkv row layout: [0,2048) q (16x128) | [2048,2560) k (4x128) | [2560,4608) v (4x512)

// ---------------- fused prep: rope tables + x cast + W_attn transpose (64x64) ----------------
// grid 11008 x 256: [0,512) tables | [512,8704) cast | [8704,11008) transposeA 64x64
__global__ void prep_kernel(const float* __restrict__ x, const float* __restrict__ W_attn,
                            float* __restrict__ sinT, float* __restrict__ cosT,
                            u16* __restrict__ xb, u16* __restrict__ WbT) {
  __shared__ u16 tile[64][72];   // stride 144B: 8B-aligned rows
  const int bk = blockIdx.x, t = threadIdx.x;
  if (bk < 512) {
    int idx = bk * 256 + t;                 // 2048*64
    int l = idx >> 6, i = idx & 63;
    float inv = __expf(-((float)(2 * i) / 128.0f) * 9.210340371976184f);
    float ang = (float)l * inv;
    sinT[idx] = sinf(ang);
    cosT[idx] = cosf(ang);
  } else if (bk < 8704) {
    int i = ((bk - 512) * 256 + t) * 4;
    float4 v = *(const float4*)(x + i);
    ushort4 o;
    o.x = f2bf(v.x); o.y = f2bf(v.y); o.z = f2bf(v.z); o.w = f2bf(v.w);
    *(ushort4*)(xb + i) = o;
  } else {
    // W_attn [2048][4608] -> WbT [4608][2048], 64x64 tiles, float4 in / ushort4 out
    int idx = bk - 8704;                    // 72 x 32 tiles
    int c0 = (idx % 72) * 64, r0 = (idx / 72) * 64;
    int tc = (t & 15) * 4, tr = t >> 4;     // tr 0..15
#pragma unroll
    for (int i = 0; i < 4; ++i) {
      int r = tr + i * 16;
      float4 v = *(const float4*)(W_attn + (size_t)(r0 + r) * 4608 + c0 + tc);
      tile[tc + 0][r] = f2bf(v.x);
      tile[tc + 1][r] = f2bf(v.y);
      tile[tc + 2][r] = f2bf(v.z);
      tile[tc + 3][r] = f2bf(v.w);
    }
    __syncthreads();
#pragma unroll
    for (int i = 0; i < 4; ++i) {
      int cc = tr + i * 16;
      ushort4 o;
      o.x = tile[cc][tc]; o.y = tile[cc][tc + 1];
      o.z = tile[cc][tc + 2]; o.w = tile[cc][tc + 3];
      *(ushort4*)(WbT + (size_t)(c0 + cc) * 2048 + r0 + tc) = o;
    }
  }
}

// ---------------- transpose + cast 64x64: fp32 [R][C] -> bf16 [C][R] (W_out) ----------------
__global__ void transpose_cast64(const float* __restrict__ in, u16* __restrict__ out,
                                 int R, int C) {
  __shared__ u16 tile[64][72];
  int c0 = blockIdx.x * 64, r0 = blockIdx.y * 64;
  int t = threadIdx.x;
  int tc = (t & 15) * 4, tr = t >> 4;
#pragma unroll
  for (int i = 0; i < 4; ++i) {
    int r = tr + i * 16;
    float4 v = *(const float4*)(in + (size_t)(r0 + r) * C + c0 + tc);
    tile[tc + 0][r] = f2bf(v.x);
    tile[tc + 1][r] = f2bf(v.y);
    tile[tc + 2][r] = f2bf(v.z);
    tile[tc + 3][r] = f2bf(v.w);
  }
  __syncthreads();
#pragma unroll
  for (int i = 0; i < 4; ++i) {
    int cc = tr + i * 16;
    ushort4 o;
    o.x = tile[cc][tc]; o.y = tile[cc][tc + 1];
    o.z = tile[cc][tc + 2]; o.w = tile[cc][tc + 3];
    *(ushort4*)(out + (size_t)(c0 + cc) * R + r0 + tc) = o;
  }
}

// ================= GEMM1: qkv = xb @ WbT^T ================= (R11-validated, 8-phase 256^2)
__global__ __launch_bounds__(512) void gemm1_8ph(const u16* __restrict__ A,
                                                 const u16* __restrict__ Bt,
                                                 u16* __restrict__ C) {
  constexpr int K = 2048, N = 4608, NT = 32;   // NT = K/64
  __shared__ __align__(16) u16 lA[2][2][8192];
  __shared__ __align__(16) u16 lB[2][2][8192];
  const int t = threadIdx.x, w = t >> 6, l = t & 63;
  const int lr = l & 15, lg = l >> 4;
  const int wr = w >> 2, wn = w & 3;
  const int swz = (blockIdx.x & 7) * 36 + (blockIdx.x >> 3);  // 288 blocks, XCD-chunked
  const int bm = swz & 15, bn = swz >> 4;                      // 16 x 18

  const size_t aBase = (size_t)(bm * 256) * K;
  const size_t bBase = (size_t)(bn * 256) * K;
  const int lslog = (t & 3) ^ ((t >> 3) & 3);     // staging: logical slot for linear dest
  const int r128 = t >> 2;
  const int aswz = (lg ^ ((lr >> 1) & 3)) << 4;   // frag-read physical slot byte offset

  auto stA = [&](int buf, int kk, int tile) {
#pragma unroll
    for (int i = 0; i < 2; ++i) {
      int row = i * 128 + r128;
      glds16(A + aBase + (size_t)row * K + tile * 64 + kk * 32 + lslog * 8,
             &lA[buf][kk][i * 4096 + t * 8]);
    }
  };
  auto stB = [&](int buf, int kk, int tile) {
#pragma unroll
    for (int i = 0; i < 2; ++i) {
      int row = i * 128 + r128;
      glds16(Bt + bBase + (size_t)row * K + tile * 64 + kk * 32 + lslog * 8,
             &lB[buf][kk][i * 4096 + t * 8]);
    }
  };

  f32x4 acc[8][4];
#pragma unroll
  for (int f = 0; f < 8; ++f)
#pragma unroll
    for (int g = 0; g < 4; ++g) acc[f][g] = f32x4{0.f, 0.f, 0.f, 0.f};

  // prologue: 12 loads out; vmcnt(8) completes (0,0,t0); barrier certifies it.
  stA(0, 0, 0); stB(0, 0, 0); stA(0, 1, 0); stB(0, 1, 0); stA(1, 0, 1); stB(1, 0, 1);
  VMCNT(8);
  barrier_raw();

  auto PH = [&](int buf, int kk, int mh, auto&& st) {
    bf16x8 af[4], bb[4];
    const char* pA = (const char*)lA[buf][kk];
    const char* pB = (const char*)lB[buf][kk];
#pragma unroll
    for (int f = 0; f < 4; ++f) {
      af[f] = *(const bf16x8*)(pA + (wr * 128 + (mh * 4 + f) * 16 + lr) * 64 + aswz);
      bb[f] = *(const bf16x8*)(pB + (wn * 64 + f * 16 + lr) * 64 + aswz);
    }
    st();
    __builtin_amdgcn_s_setprio(1);
#pragma unroll
    for (int f = 0; f < 4; ++f)
#pragma unroll
      for (int g = 0; g < 4; ++g)
        acc[mh * 4 + f][g] = MFMA(af[f], bb[g], acc[mh * 4 + f][g]);
    __builtin_amdgcn_s_setprio(0);
  };
  auto NOST = [] {};

  for (int i = 0; i < NT / 2 - 1; ++i) {
    const int t1 = 2 * i + 1, t2 = 2 * i + 2, t3 = 2 * i + 3;
    PH(0, 0, 0, [&] { stA(1, 1, t1); });            barrier_raw();
    PH(0, 0, 1, [&] { stB(1, 1, t1); }); VMCNT(8);  barrier_raw();
    PH(0, 1, 0, [&] { stA(0, 0, t2); });            barrier_raw();
    PH(0, 1, 1, [&] { stB(0, 0, t2); }); VMCNT(8);  barrier_raw();
    PH(1, 0, 0, [&] { stA(0, 1, t2); });            barrier_raw();
    PH(1, 0, 1, [&] { stB(0, 1, t2); }); VMCNT(8);  barrier_raw();
    PH(1, 1, 0, [&] { stA(1, 0, t3); });            barrier_raw();
    PH(1, 1, 1, [&] { stB(1, 0, t3); }); VMCNT(8);  barrier_raw();
  }
  // peel: tiles NT-2 (buf0, certified), NT-1 (buf1). Waits drain 8 -> 4 -> 0.
  PH(0, 0, 0, [&] { stA(1, 1, NT - 1); });           barrier_raw();
  PH(0, 0, 1, [&] { stB(1, 1, NT - 1); }); VMCNT(8); barrier_raw();
  PH(0, 1, 0, NOST);                                 barrier_raw();
  PH(0, 1, 1, NOST);                       VMCNT(4); barrier_raw();
  PH(1, 0, 0, NOST);                                 barrier_raw();
  PH(1, 0, 1, NOST);                       VMCNT(0); barrier_raw();
  PH(1, 1, 0, NOST);                                 barrier_raw();
  PH(1, 1, 1, NOST);

  const int crow0 = bm * 256 + wr * 128;
  const int ccol0 = bn * 256 + wn * 64;
#pragma unroll
  for (int f = 0; f < 8; ++f)
#pragma unroll
    for (int g = 0; g < 4; ++g)
#pragma unroll
      for (int j = 0; j < 4; ++j)
        C[(size_t)(crow0 + f * 16 + lg * 4 + j) * N + ccol0 + g * 16 + lr] =
            f2bf(acc[f][g][j]);
}

// ================= GEMM2: out = ctxb @ WobT^T + bias ================= (R6-validated)
template <int WRITE_F32, int K, int N>
__global__ __launch_bounds__(512) void gemm_4ph(const u16* __restrict__ A,
                                                const u16* __restrict__ Bt,
                                                u16* __restrict__ Cb,
                                                float* __restrict__ Cf,
                                                const float* __restrict__ bias) {
  constexpr int NT = K / 64;
  constexpr int NBN = N / 128;
  __shared__ __align__(16) u16 lA[2][2][8192];   // 64KB
  __shared__ __align__(16) u16 lB[2][2][4096];   // 32KB
  const int t = threadIdx.x, w = t >> 6, l = t & 63;
  const int lr = l & 15, lg = l >> 4;
  const int wr = w >> 1, wn = w & 1;
  const int swz = (blockIdx.x & 7) * (2 * NBN) + (blockIdx.x >> 3);  // 16*NBN blocks
  const int bm = swz & 15, bn = swz >> 4;

  const size_t aBase = (size_t)(bm * 256) * K;
  const size_t bBase = (size_t)(bn * 128) * K;
  const int lslog = (t & 3) ^ ((t >> 3) & 3);
  const int r128 = t >> 2;
  const int aswz = (lg ^ ((lr >> 1) & 3)) << 4;

  auto stA = [&](int buf, int kk, int tile) {
#pragma unroll
    for (int i = 0; i < 2; ++i) {
      int row = i * 128 + r128;
      glds16(A + aBase + (size_t)row * K + tile * 64 + kk * 32 + lslog * 8,
             &lA[buf][kk][i * 4096 + t * 8]);
    }
  };
  auto stB = [&](int buf, int kk, int tile) {
    glds16(Bt + bBase + (size_t)r128 * K + tile * 64 + kk * 32 + lslog * 8,
           &lB[buf][kk][t * 8]);
  };

  f32x4 acc[4][4];
#pragma unroll
  for (int f = 0; f < 4; ++f)
#pragma unroll
    for (int g = 0; g < 4; ++g) acc[f][g] = f32x4{0.f, 0.f, 0.f, 0.f};

  // prologue: 9 loads; vmcnt(6) completes (0,0,t0); barrier certifies.
  stA(0, 0, 0); stB(0, 0, 0); stA(0, 1, 0); stB(0, 1, 0); stA(1, 0, 1); stB(1, 0, 1);
  VMCNT(6);
  barrier_raw();

  auto PH = [&](int buf, int kk, auto&& st) {
    bf16x8 af[4], bb[4];
    const char* pA = (const char*)lA[buf][kk];
    const char* pB = (const char*)lB[buf][kk];
#pragma unroll
    for (int f = 0; f < 4; ++f) {
      af[f] = *(const bf16x8*)(pA + (wr * 64 + f * 16 + lr) * 64 + aswz);
      bb[f] = *(const bf16x8*)(pB + (wn * 64 + f * 16 + lr) * 64 + aswz);
    }
    st();
    __builtin_amdgcn_s_setprio(1);
#pragma unroll
    for (int f = 0; f < 4; ++f)
#pragma unroll
      for (int g = 0; g < 4; ++g)
        acc[f][g] = MFMA(af[f], bb[g], acc[f][g]);
    __builtin_amdgcn_s_setprio(0);
  };
  auto NOST = [] {};

  for (int i = 0; i < NT / 2 - 1; ++i) {
    const int t1 = 2 * i + 1, t2 = 2 * i + 2, t3 = 2 * i + 3;
    PH(0, 0, [&] { stA(1, 1, t1); stB(1, 1, t1); }); VMCNT(6); barrier_raw();
    PH(0, 1, [&] { stA(0, 0, t2); stB(0, 0, t2); }); VMCNT(6); barrier_raw();
    PH(1, 0, [&] { stA(0, 1, t2); stB(0, 1, t2); }); VMCNT(6); barrier_raw();
    PH(1, 1, [&] { stA(1, 0, t3); stB(1, 0, t3); }); VMCNT(6); barrier_raw();
  }
  // peel: tiles NT-2 (buf0, certified), NT-1 (buf1). Waits 6 -> 3 -> 0.
  PH(0, 0, [&] { stA(1, 1, NT - 1); stB(1, 1, NT - 1); }); VMCNT(6); barrier_raw();
  PH(0, 1, NOST);                                          VMCNT(3); barrier_raw();
  PH(1, 0, NOST);                                          VMCNT(0); barrier_raw();
  PH(1, 1, NOST);

  const int crow0 = bm * 256 + wr * 64;
  const int ccol0 = bn * 128 + wn * 64;
#pragma unroll
  for (int g = 0; g < 4; ++g) {
    float bv = WRITE_F32 ? bias[ccol0 + g * 16 + lr] : 0.f;
#pragma unroll
    for (int f = 0; f < 4; ++f)
#pragma unroll
      for (int j = 0; j < 4; ++j) {
        size_t off = (size_t)(crow0 + f * 16 + lg * 4 + j) * N + ccol0 + g * 16 + lr;
        if (WRITE_F32) Cf[off] = acc[f][g][j] + bv;
        else           Cb[off] = f2bf(acc[f][g][j]);
      }
  }
}

// ---------------- fused rope + V^T, vectorized (ushort4) ----------------
// grid 7168 x 256: [0,5120) rope x4-wide | [5120,7168) vt 64x64 tiles
// rope: thread handles 4 consecutive d; identical arithmetic to R15.
// vt: pi(k)=((k>>2)&3)*8+((k>>4)&1)*4+(k&3) is identity on low 2 bits, so 4
//     consecutive aligned l map to 4 consecutive output columns -> ushort4 ok.
__global__ void ropevt_kernel(u16* __restrict__ qkv, const float* __restrict__ sinT,
                              const float* __restrict__ cosT, u16* __restrict__ vT) {
  __shared__ u16 tile[64][72];
  const int bk = blockIdx.x, t = threadIdx.x;
  if (bk < 5120) {
    int idx = bk * 256 + t;                 // 4096 rows * 20 heads * 16 (x4 d)
    int d4 = (idx & 15) * 4;
    int rh = idx >> 4;
    int head = rh % 20;
    int row = rh / 20;
    int lpos = row & 2047;
    int col = head < 16 ? head * 128 : 2048 + (head - 16) * 128;
    float sc = head < 16 ? 0.12751743561938476f : 1.0f;   // log2e/sqrt(128) into Q
    u16* p = qkv + (size_t)row * 4608 + col;
    ushort4 v1 = *(const ushort4*)(p + d4);
    ushort4 v2 = *(const ushort4*)(p + d4 + 64);
    float4 cs = *(const float4*)(cosT + lpos * 64 + d4);
    float4 sn = *(const float4*)(sinT + lpos * 64 + d4);
    ushort4 o1, o2;
    o1.x = f2bf((bf2f(v1.x) * cs.x - bf2f(v2.x) * sn.x) * sc);
    o1.y = f2bf((bf2f(v1.y) * cs.y - bf2f(v2.y) * sn.y) * sc);
    o1.z = f2bf((bf2f(v1.z) * cs.z - bf2f(v2.z) * sn.z) * sc);
    o1.w = f2bf((bf2f(v1.w) * cs.w - bf2f(v2.w) * sn.w) * sc);
    o2.x = f2bf((bf2f(v2.x) * cs.x + bf2f(v1.x) * sn.x) * sc);
    o2.y = f2bf((bf2f(v2.y) * cs.y + bf2f(v1.y) * sn.y) * sc);
    o2.z = f2bf((bf2f(v2.z) * cs.z + bf2f(v1.z) * sn.z) * sc);
    o2.w = f2bf((bf2f(v2.w) * cs.w + bf2f(v1.w) * sn.w) * sc);
    *(ushort4*)(p + d4)      = o1;
    *(ushort4*)(p + d4 + 64) = o2;
  } else {
    // vT[(b*4+kv)*512 + e][32-group(l) + pi(l&31)] = V[l][e]
    int idx = bk - 5120;                    // 8 e-tiles x 32 l-tiles x 8 bkv
    int ex = idx & 7, ly = (idx >> 3) & 31, bkv = idx >> 8;
    int b = bkv >> 2, kv = bkv & 3;
    int e0 = ex * 64, l0 = ly * 64;
    const u16* src = qkv + (size_t)(b * 2048) * 4608 + 2560 + kv * 512;
    int tc = (t & 15) * 4, tr = t >> 4;     // tr 0..15
#pragma unroll
    for (int i = 0; i < 4; ++i) {
      int lrow = tr + i * 16;
      ushort4 v = *(const ushort4*)(src + (size_t)(l0 + lrow) * 4608 + e0 + tc);
      tile[tc + 0][lrow] = v.x;
      tile[tc + 1][lrow] = v.y;
      tile[tc + 2][lrow] = v.z;
      tile[tc + 3][lrow] = v.w;
    }
    __syncthreads();
    u16* dst = vT + (size_t)(bkv * 512) * 2048;
    const int colb = l0 + ((tc >> 5) & 1) * 32 + ((tc >> 2) & 3) * 8 + ((tc >> 4) & 1) * 4;
#pragma unroll
    for (int i = 0; i < 4; ++i) {
      int er = tr + i * 16;
      ushort4 o;
      o.x = tile[er][tc]; o.y = tile[er][tc + 1];
      o.z = tile[er][tc + 2]; o.w = tile[er][tc + 3];
      *(ushort4*)(dst + (size_t)(e0 + er) * 2048 + colb) = o;
    }
  }
}

// ---------------- flash attention v8 (R11-validated): KVBLK=64, shuffle-free ----------------
__global__ __launch_bounds__(512, 2) void attn_kernel(
    const u16* __restrict__ qkv, const u16* __restrict__ vT,
    u16* __restrict__ ctxb) {
  const int wg = blockIdx.x;
  const int pg = wg & 7, qt = wg >> 3;
  const int kvg = pg & 3, b = pg >> 2;
  const int t = threadIdx.x, w = t >> 6, l = t & 63;
  const int lr = l & 15, lg = l >> 4;
  const int h4 = w >> 1, eh = w & 1;
  const int h = kvg * 4 + h4;

  __shared__ __align__(16) u16 lK[2][64 * 128];   // 2 x 16KB
  __shared__ __align__(16) u16 lV[2][512 * 64];   // 2 x 64KB

  f32x4 zero = {0.f, 0.f, 0.f, 0.f};

  bf16x8 qf[2][4];
  const size_t qbase = (size_t)(b * 2048 + qt * 32);
#pragma unroll
  for (int m = 0; m < 2; ++m)
#pragma unroll
    for (int dc = 0; dc < 4; ++dc)
      qf[m][dc] = *(const bf16x8*)(qkv + (qbase + m * 16 + lr) * 4608 + h * 128 + dc * 32 + lg * 8);

  f32x4 acc[2][16];
#pragma unroll
  for (int m = 0; m < 2; ++m)
#pragma unroll
    for (int e = 0; e < 16; ++e) acc[m][e] = zero;
  float m_r[2] = {-1e30f, -1e30f};   // log2-domain running max (per q = lr)
  float l_r[2] = {0.f, 0.f};         // per-lane partial denominators

  const size_t kbase = (size_t)(b * 2048) * 4608 + 2048 + kvg * 128;
  const size_t vbase = (size_t)((b * 4 + kvg) * 512) * 2048;

  const int krow = t >> 4;
  const int kp = t & 15;
  const int ks = (kp & 8) | ((kp ^ (krow & 7)) & 7);
  const u16* ksrc0 = qkv + kbase + (size_t)krow * 4608 + ks * 8;
  const int vs = (t & 7) ^ ((t >> 3) & 7);
  const int ve0 = (t >> 3) * 2 + (vs >> 2);
  const u16* vsrc0 = vT + vbase + (size_t)ve0 * 2048 + (vs & 3) * 8;

  const int vfoff = (eh * 128 + (lr >> 1)) * 128 +
                    (((((lr & 1) << 2) | lg) ^ ((lr >> 1) & 7)) << 4);

  auto stage = [&](int bi, int kv0) {
#pragma unroll
    for (int i = 0; i < 2; ++i)
      glds16(ksrc0 + (size_t)(kv0 + i * 32) * 4608, &lK[bi][i * 4096 + t * 8]);
#pragma unroll
    for (int hh = 0; hh < 2; ++hh)
#pragma unroll
      for (int i = 0; i < 4; ++i)
        glds16(vsrc0 + (kv0 + hh * 32) + (size_t)i * 262144,
               &lV[bi][hh * 16384 + i * 4096 + t * 8]);
  };

  stage(0, 0);

  auto half_body = [&](const char* lKc, const char* lVc) {
    f32x4 sT[2][2];
    sT[0][0] = zero; sT[0][1] = zero; sT[1][0] = zero; sT[1][1] = zero;
    __builtin_amdgcn_s_setprio(1);
#pragma unroll
    for (int dc = 0; dc < 4; ++dc) {
      int slot = dc * 4 + lg;
      int sw = (slot & 8) | ((slot ^ (lr & 7)) & 7);
#pragma unroll
      for (int kt = 0; kt < 2; ++kt) {
        bf16x8 kf = *(const bf16x8*)(lKc + (kt * 16 + lr) * 256 + sw * 16);
        sT[kt][0] = MFMA(kf, qf[0][dc], sT[kt][0]);
        sT[kt][1] = MFMA(kf, qf[1][dc], sT[kt][1]);
      }
    }
    __builtin_amdgcn_s_setprio(0);

    float lmax[2];
#pragma unroll
    for (int m = 0; m < 2; ++m) {
      float a0 = fmaxf(fmaxf(sT[0][m][0], sT[0][m][1]), fmaxf(sT[0][m][2], sT[0][m][3]));
      float a1 = fmaxf(fmaxf(sT[1][m][0], sT[1][m][1]), fmaxf(sT[1][m][2], sT[1][m][3]));
      lmax[m] = fmaxf(a0, a1);
    }
    bool need = (lmax[0] > m_r[0] + 11.5f) || (lmax[1] > m_r[1] + 11.5f);
    if (__any(need)) {                      // rare: reduce, rescale acc & partials
#pragma unroll
      for (int m = 0; m < 2; ++m) {
        float r = lmax[m];
        r = fmaxf(r, __shfl_xor(r, 16));
        r = fmaxf(r, __shfl_xor(r, 32));
        float mn = fmaxf(m_r[m], r);
        float al = ex2(m_r[m] - mn);
        m_r[m] = mn; l_r[m] *= al;
        float alj[4];
#pragma unroll
        for (int j = 0; j < 4; ++j) alj[j] = __shfl(al, lg * 4 + j);
#pragma unroll
        for (int e = 0; e < 16; ++e)
#pragma unroll
          for (int j = 0; j < 4; ++j) acc[m][e][j] *= alj[j];
      }
    }

    bf16x8 pf[2];
#pragma unroll
    for (int m = 0; m < 2; ++m) {
      float p0 = ex2(sT[0][m][0] - m_r[m]), p1 = ex2(sT[0][m][1] - m_r[m]);
      float p2 = ex2(sT[0][m][2] - m_r[m]), p3 = ex2(sT[0][m][3] - m_r[m]);
      float p4 = ex2(sT[1][m][0] - m_r[m]), p5 = ex2(sT[1][m][1] - m_r[m]);
      float p6 = ex2(sT[1][m][2] - m_r[m]), p7 = ex2(sT[1][m][3] - m_r[m]);
      l_r[m] += ((p0 + p1) + (p2 + p3)) + ((p4 + p5) + (p6 + p7));
      union { bf16x8 v; unsigned wd[4]; } u;
      u.wd[0] = cvt_pk_bf16(p0, p1);
      u.wd[1] = cvt_pk_bf16(p2, p3);
      u.wd[2] = cvt_pk_bf16(p4, p5);
      u.wd[3] = cvt_pk_bf16(p6, p7);
      pf[m] = u.v;
    }

    __builtin_amdgcn_s_setprio(1);
#pragma unroll
    for (int e = 0; e < 16; ++e) {
      bf16x8 vf = *(const bf16x8*)(lVc + vfoff + e * 1024);
      acc[0][e] = MFMA(pf[0], vf, acc[0][e]);
      acc[1][e] = MFMA(pf[1], vf, acc[1][e]);
    }
    __builtin_amdgcn_s_setprio(0);
  };

  for (int it = 0; it < 32; ++it) {
    const int cur = it & 1;
    __syncthreads();                         // certify tile(it); drains all reads
    if (it + 1 < 32) stage(cur ^ 1, 64 * (it + 1));
    const char* lKc = (const char*)lK[cur];
    const char* lVc = (const char*)lV[cur];
    half_body(lKc, lVc);                     // kv [64it, 64it+32)
    half_body(lKc + 8192, lVc + 32768);      // kv [64it+32, 64it+64)
  }

  // ---- epilogue: deferred l_r reduction, then normalize & store ----
#pragma unroll
  for (int m = 0; m < 2; ++m) {
    float s = l_r[m];
    s += __shfl_xor(s, 16);
    s += __shfl_xor(s, 32);
    l_r[m] = s;
  }
#pragma unroll
  for (int m = 0; m < 2; ++m) {
    float linv[4];
#pragma unroll
    for (int j = 0; j < 4; ++j) linv[j] = 1.0f / __shfl(l_r[m], lg * 4 + j);
    const size_t orow0 = qbase + m * 16 + lg * 4;
#pragma unroll
    for (int e = 0; e < 16; ++e)
#pragma unroll
      for (int j = 0; j < 4; ++j)
        ctxb[(orow0 + j) * 8192 + h * 512 + eh * 256 + e * 16 + lr] =
            f2bf(acc[m][e][j] * linv[j]);
  }
}

// ---------------- launch ----------------
extern "C" void kernel_launch(void* const* d_in, const int* in_sizes, int n_in,
                              void* d_out, int out_size, void* d_ws, size_t ws_size,
                              hipStream_t stream) {
  const float* x      = (const float*)d_in[0];
  const float* W_attn = (const float*)d_in[1];
  const float* W_out  = (const float*)d_in[2];
  const float* b_out  = (const float*)d_in[3];
  float* out = (float*)d_out;
  char* ws = (char*)d_ws;

  if (ws_size < 158334976u) return;  // need ~151MB scratch

  float* sinT = (float*)(ws + 0);
  float* cosT = (float*)(ws + 524288);
  u16* xb   = (u16*)(ws + 1048576);    // 16MB   (dead after GEMM1)
  u16* WbT  = (u16*)(ws + 17825792);   // 18MB   (dead after GEMM1)
  u16* qkvb = (u16*)(ws + 36700160);   // 36MB
  u16* vT   = (u16*)(ws + 74448896);   // 16MB
  u16* ctxb = (u16*)(ws + 91226112);   // 64MB
  u16* WobT = (u16*)(ws + 1048576);    // 32MB, reuses xb+WbT region post-GEMM1

  prep_kernel<<<11008, 256, 0, stream>>>(x, W_attn, sinT, cosT, xb, WbT);
  gemm1_8ph<<<288, 512, 0, stream>>>(xb, WbT, qkvb);
  ropevt_kernel<<<7168, 256, 0, stream>>>(qkvb, sinT, cosT, vT);
  attn_kernel<<<512, 512, 0, stream>>>(qkvb, vT, ctxb);
  transpose_cast64<<<dim3(32, 128), 256, 0, stream>>>(W_out, WobT, 8192, 2048);
  gemm_4ph<1, 8192, 2048><<<256, 512, 0, stream>>>(ctxb, WobT, nullptr, out, b_out);
}

// Round 18
// 548.191 us; speedup vs baseline: 1.0039x; 1.0039x over previous
//
#include <hip/hip_runtime.h>

typedef unsigned short u16;
typedef float f32x4 __attribute__((ext_vector_type(4)));
typedef __bf16 bf16x8 __attribute__((ext_vector_type(8)));

#define DEV static __device__ __forceinline__

DEV u16 f2bf(float f) {
  union { float f; unsigned u; } c; c.f = f;
  unsigned u = c.u;
  u += 0x7fffu + ((u >> 16) & 1u);   // RNE; inputs are normal floats
  return (u16)(u >> 16);
}
DEV float bf2f(u16 h) {
  union { float f; unsigned u; } c; c.u = ((unsigned)h) << 16;
  return c.f;
}
DEV f32x4 MFMA(bf16x8 a, bf16x8 b, f32x4 c) {
  return __builtin_amdgcn_mfma_f32_16x16x32_bf16(a, b, c, 0, 0, 0);
}
DEV unsigned cvt_pk_bf16(float a, float b) {   // low16 = a, high16 = b (RNE)
  unsigned r;
  asm("v_cvt_pk_bf16_f32 %0, %1, %2" : "=v"(r) : "v"(a), "v"(b));
  return r;
}
DEV float ex2(float x) { return __builtin_amdgcn_exp2f(x); }
DEV void glds16(const void* src, void* lds) {   // async global->LDS, 16B/lane
  __builtin_amdgcn_global_load_lds(
      (__attribute__((address_space(1))) void*)src,
      (__attribute__((address_space(3))) void*)lds, 16, 0, 0);
}
DEV void barrier_raw() {                        // raw s_barrier: NO vmcnt drain
  __builtin_amdgcn_sched_barrier(0);
  asm volatile("s_barrier" ::: "memory");
  __builtin_amdgcn_sched_barrier(0);
}
#define VMCNT(N)                                              \
  do {                                                        \
    asm volatile("s_waitcnt vmcnt(" #N ")" ::: "memory");     \
    __builtin_amdgcn_sched_barrier(0);                        \
  } while (0)

// ---------------- constants ----------------
// B=2 L=2048 DM=2048 H=16 KV=4 GROUP=4 DK=128 DV=512
// qkv row layout: [0,2048) q (16x128) | [2048,2560) k (4x128) | [2560,4608) v (4x512)

// ---------------- fused prep: rope tables + x cast + W_attn transpose (64x64) ----------------
// grid 11008 x 256: [0,512) tables | [512,8704) cast | [8704,11008) transposeA 64x64
__global__ void prep_kernel(const float* __restrict__ x, const float* __restrict__ W_attn,
                            float* __restrict__ sinT, float* __restrict__ cosT,
                            u16* __restrict__ xb, u16* __restrict__ WbT) {
  __shared__ u16 tile[64][72];   // stride 144B: 8B-aligned rows
  const int bk = blockIdx.x, t = threadIdx.x;
  if (bk < 512) {
    int idx = bk * 256 + t;                 // 2048*64
    int l = idx >> 6, i = idx & 63;
    float inv = __expf(-((float)(2 * i) / 128.0f) * 9.210340371976184f);
    float ang = (float)l * inv;
    sinT[idx] = sinf(ang);
    cosT[idx] = cosf(ang);
  } else if (bk < 8704) {
    int i = ((bk - 512) * 256 + t) * 4;
    float4 v = *(const float4*)(x + i);
    ushort4 o;
    o.x = f2bf(v.x); o.y = f2bf(v.y); o.z = f2bf(v.z); o.w = f2bf(v.w);
    *(ushort4*)(xb + i) = o;
  } else {
    // W_attn [2048][4608] -> WbT [4608][2048], 64x64 tiles, float4 in / ushort4 out
    int idx = bk - 8704;                    // 72 x 32 tiles
    int c0 = (idx % 72) * 64, r0 = (idx / 72) * 64;
    int tc = (t & 15) * 4, tr = t >> 4;     // tr 0..15
#pragma unroll
    for (int i = 0; i < 4; ++i) {
      int r = tr + i * 16;
      float4 v = *(const float4*)(W_attn + (size_t)(r0 + r) * 4608 + c0 + tc);
      tile[tc + 0][r] = f2bf(v.x);
      tile[tc + 1][r] = f2bf(v.y);
      tile[tc + 2][r] = f2bf(v.z);
      tile[tc + 3][r] = f2bf(v.w);
    }
    __syncthreads();
#pragma unroll
    for (int i = 0; i < 4; ++i) {
      int cc = tr + i * 16;
      ushort4 o;
      o.x = tile[cc][tc]; o.y = tile[cc][tc + 1];
      o.z = tile[cc][tc + 2]; o.w = tile[cc][tc + 3];
      *(ushort4*)(WbT + (size_t)(c0 + cc) * 2048 + r0 + tc) = o;
    }
  }
}

// ================= GEMM1: qkv = xb @ WbT^T ================= (R11-validated, 8-phase 256^2)
__global__ __launch_bounds__(512) void gemm1_8ph(const u16* __restrict__ A,
                                                 const u16* __restrict__ Bt,
                                                 u16* __restrict__ C) {
  constexpr int K = 2048, N = 4608, NT = 32;   // NT = K/64
  __shared__ __align__(16) u16 lA[2][2][8192];
  __shared__ __align__(16) u16 lB[2][2][8192];
  const int t = threadIdx.x, w = t >> 6, l = t & 63;
  const int lr = l & 15, lg = l >> 4;
  const int wr = w >> 2, wn = w & 3;
  const int swz = (blockIdx.x & 7) * 36 + (blockIdx.x >> 3);  // 288 blocks, XCD-chunked
  const int bm = swz & 15, bn = swz >> 4;                      // 16 x 18

  const size_t aBase = (size_t)(bm * 256) * K;
  const size_t bBase = (size_t)(bn * 256) * K;
  const int lslog = (t & 3) ^ ((t >> 3) & 3);     // staging: logical slot for linear dest
  const int r128 = t >> 2;
  const int aswz = (lg ^ ((lr >> 1) & 3)) << 4;   // frag-read physical slot byte offset

  auto stA = [&](int buf, int kk, int tile) {
#pragma unroll
    for (int i = 0; i < 2; ++i) {
      int row = i * 128 + r128;
      glds16(A + aBase + (size_t)row * K + tile * 64 + kk * 32 + lslog * 8,
             &lA[buf][kk][i * 4096 + t * 8]);
    }
  };
  auto stB = [&](int buf, int kk, int tile) {
#pragma unroll
    for (int i = 0; i < 2; ++i) {
      int row = i * 128 + r128;
      glds16(Bt + bBase + (size_t)row * K + tile * 64 + kk * 32 + lslog * 8,
             &lB[buf][kk][i * 4096 + t * 8]);
    }
  };

  f32x4 acc[8][4];
#pragma unroll
  for (int f = 0; f < 8; ++f)
#pragma unroll
    for (int g = 0; g < 4; ++g) acc[f][g] = f32x4{0.f, 0.f, 0.f, 0.f};

  // prologue: 12 loads out; vmcnt(8) completes (0,0,t0); barrier certifies it.
  stA(0, 0, 0); stB(0, 0, 0); stA(0, 1, 0); stB(0, 1, 0); stA(1, 0, 1); stB(1, 0, 1);
  VMCNT(8);
  barrier_raw();

  auto PH = [&](int buf, int kk, int mh, auto&& st) {
    bf16x8 af[4], bb[4];
    const char* pA = (const char*)lA[buf][kk];
    const char* pB = (const char*)lB[buf][kk];
#pragma unroll
    for (int f = 0; f < 4; ++f) {
      af[f] = *(const bf16x8*)(pA + (wr * 128 + (mh * 4 + f) * 16 + lr) * 64 + aswz);
      bb[f] = *(const bf16x8*)(pB + (wn * 64 + f * 16 + lr) * 64 + aswz);
    }
    st();
    __builtin_amdgcn_s_setprio(1);
#pragma unroll
    for (int f = 0; f < 4; ++f)
#pragma unroll
      for (int g = 0; g < 4; ++g)
        acc[mh * 4 + f][g] = MFMA(af[f], bb[g], acc[mh * 4 + f][g]);
    __builtin_amdgcn_s_setprio(0);
  };
  auto NOST = [] {};

  for (int i = 0; i < NT / 2 - 1; ++i) {
    const int t1 = 2 * i + 1, t2 = 2 * i + 2, t3 = 2 * i + 3;
    PH(0, 0, 0, [&] { stA(1, 1, t1); });            barrier_raw();
    PH(0, 0, 1, [&] { stB(1, 1, t1); }); VMCNT(8);  barrier_raw();
    PH(0, 1, 0, [&] { stA(0, 0, t2); });            barrier_raw();
    PH(0, 1, 1, [&] { stB(0, 0, t2); }); VMCNT(8);  barrier_raw();
    PH(1, 0, 0, [&] { stA(0, 1, t2); });            barrier_raw();
    PH(1, 0, 1, [&] { stB(0, 1, t2); }); VMCNT(8);  barrier_raw();
    PH(1, 1, 0, [&] { stA(1, 0, t3); });            barrier_raw();
    PH(1, 1, 1, [&] { stB(1, 0, t3); }); VMCNT(8);  barrier_raw();
  }
  // peel: tiles NT-2 (buf0, certified), NT-1 (buf1). Waits drain 8 -> 4 -> 0.
  PH(0, 0, 0, [&] { stA(1, 1, NT - 1); });           barrier_raw();
  PH(0, 0, 1, [&] { stB(1, 1, NT - 1); }); VMCNT(8); barrier_raw();
  PH(0, 1, 0, NOST);                                 barrier_raw();
  PH(0, 1, 1, NOST);                       VMCNT(4); barrier_raw();
  PH(1, 0, 0, NOST);                                 barrier_raw();
  PH(1, 0, 1, NOST);                       VMCNT(0); barrier_raw();
  PH(1, 1, 0, NOST);                                 barrier_raw();
  PH(1, 1, 1, NOST);

  const int crow0 = bm * 256 + wr * 128;
  const int ccol0 = bn * 256 + wn * 64;
#pragma unroll
  for (int f = 0; f < 8; ++f)
#pragma unroll
    for (int g = 0; g < 4; ++g)
#pragma unroll
      for (int j = 0; j < 4; ++j)
        C[(size_t)(crow0 + f * 16 + lg * 4 + j) * N + ccol0 + g * 16 + lr] =
            f2bf(acc[f][g][j]);
}

// ================= GEMM2: out = ctxb @ WobT^T + bias ================= (R6-validated)
template <int WRITE_F32, int K, int N>
__global__ __launch_bounds__(512) void gemm_4ph(const u16* __restrict__ A,
                                                const u16* __restrict__ Bt,
                                                u16* __restrict__ Cb,
                                                float* __restrict__ Cf,
                                                const float* __restrict__ bias) {
  constexpr int NT = K / 64;
  constexpr int NBN = N / 128;
  __shared__ __align__(16) u16 lA[2][2][8192];   // 64KB
  __shared__ __align__(16) u16 lB[2][2][4096];   // 32KB
  const int t = threadIdx.x, w = t >> 6, l = t & 63;
  const int lr = l & 15, lg = l >> 4;
  const int wr = w >> 1, wn = w & 1;
  const int swz = (blockIdx.x & 7) * (2 * NBN) + (blockIdx.x >> 3);  // 16*NBN blocks
  const int bm = swz & 15, bn = swz >> 4;

  const size_t aBase = (size_t)(bm * 256) * K;
  const size_t bBase = (size_t)(bn * 128) * K;
  const int lslog = (t & 3) ^ ((t >> 3) & 3);
  const int r128 = t >> 2;
  const int aswz = (lg ^ ((lr >> 1) & 3)) << 4;

  auto stA = [&](int buf, int kk, int tile) {
#pragma unroll
    for (int i = 0; i < 2; ++i) {
      int row = i * 128 + r128;
      glds16(A + aBase + (size_t)row * K + tile * 64 + kk * 32 + lslog * 8,
             &lA[buf][kk][i * 4096 + t * 8]);
    }
  };
  auto stB = [&](int buf, int kk, int tile) {
    glds16(Bt + bBase + (size_t)r128 * K + tile * 64 + kk * 32 + lslog * 8,
           &lB[buf][kk][t * 8]);
  };

  f32x4 acc[4][4];
#pragma unroll
  for (int f = 0; f < 4; ++f)
#pragma unroll
    for (int g = 0; g < 4; ++g) acc[f][g] = f32x4{0.f, 0.f, 0.f, 0.f};

  // prologue: 9 loads; vmcnt(6) completes (0,0,t0); barrier certifies.
  stA(0, 0, 0); stB(0, 0, 0); stA(0, 1, 0); stB(0, 1, 0); stA(1, 0, 1); stB(1, 0, 1);
  VMCNT(6);
  barrier_raw();

  auto PH = [&](int buf, int kk, auto&& st) {
    bf16x8 af[4], bb[4];
    const char* pA = (const char*)lA[buf][kk];
    const char* pB = (const char*)lB[buf][kk];
#pragma unroll
    for (int f = 0; f < 4; ++f) {
      af[f] = *(const bf16x8*)(pA + (wr * 64 + f * 16 + lr) * 64 + aswz);
      bb[f] = *(const bf16x8*)(pB + (wn * 64 + f * 16 + lr) * 64 + aswz);
    }
    st();
    __builtin_amdgcn_s_setprio(1);
#pragma unroll
    for (int f = 0; f < 4; ++f)
#pragma unroll
      for (int g = 0; g < 4; ++g)
        acc[f][g] = MFMA(af[f], bb[g], acc[f][g]);
    __builtin_amdgcn_s_setprio(0);
  };
  auto NOST = [] {};

  for (int i = 0; i < NT / 2 - 1; ++i) {
    const int t1 = 2 * i + 1, t2 = 2 * i + 2, t3 = 2 * i + 3;
    PH(0, 0, [&] { stA(1, 1, t1); stB(1, 1, t1); }); VMCNT(6); barrier_raw();
    PH(0, 1, [&] { stA(0, 0, t2); stB(0, 0, t2); }); VMCNT(6); barrier_raw();
    PH(1, 0, [&] { stA(0, 1, t2); stB(0, 1, t2); }); VMCNT(6); barrier_raw();
    PH(1, 1, [&] { stA(1, 0, t3); stB(1, 0, t3); }); VMCNT(6); barrier_raw();
  }
  // peel: tiles NT-2 (buf0, certified), NT-1 (buf1). Waits 6 -> 3 -> 0.
  PH(0, 0, [&] { stA(1, 1, NT - 1); stB(1, 1, NT - 1); }); VMCNT(6); barrier_raw();
  PH(0, 1, NOST);                                          VMCNT(3); barrier_raw();
  PH(1, 0, NOST);                                          VMCNT(0); barrier_raw();
  PH(1, 1, NOST);

  const int crow0 = bm * 256 + wr * 64;
  const int ccol0 = bn * 128 + wn * 64;
#pragma unroll
  for (int g = 0; g < 4; ++g) {
    float bv = WRITE_F32 ? bias[ccol0 + g * 16 + lr] : 0.f;
#pragma unroll
    for (int f = 0; f < 4; ++f)
#pragma unroll
      for (int j = 0; j < 4; ++j) {
        size_t off = (size_t)(crow0 + f * 16 + lg * 4 + j) * N + ccol0 + g * 16 + lr;
        if (WRITE_F32) Cf[off] = acc[f][g][j] + bv;
        else           Cb[off] = f2bf(acc[f][g][j]);
      }
  }
}

// ---------------- fused rope + V^T + W_out transpose (all post-gemm1, pre-gemm2) ----------------
// grid 11264 x 256: [0,5120) rope x4-wide | [5120,7168) vt 64x64 | [7168,11264) transposeW 64x64
// rope: thread handles 4 consecutive d; vt: pi identity on low 2 bits -> ushort4 ok.
// transposeW: W_out [8192][2048] -> WobT [2048][8192]; WobT aliases xb/WbT (dead post-gemm1).
__global__ void ropevt_kernel(u16* __restrict__ qkv, const float* __restrict__ sinT,
                              const float* __restrict__ cosT, u16* __restrict__ vT,
                              const float* __restrict__ W_out, u16* __restrict__ WobT) {
  __shared__ u16 tile[64][72];
  const int bk = blockIdx.x, t = threadIdx.x;
  if (bk < 5120) {
    int idx = bk * 256 + t;                 // 4096 rows * 20 heads * 16 (x4 d)
    int d4 = (idx & 15) * 4;
    int rh = idx >> 4;
    int head = rh % 20;
    int row = rh / 20;
    int lpos = row & 2047;
    int col = head < 16 ? head * 128 : 2048 + (head - 16) * 128;
    float sc = head < 16 ? 0.12751743561938476f : 1.0f;   // log2e/sqrt(128) into Q
    u16* p = qkv + (size_t)row * 4608 + col;
    ushort4 v1 = *(const ushort4*)(p + d4);
    ushort4 v2 = *(const ushort4*)(p + d4 + 64);
    float4 cs = *(const float4*)(cosT + lpos * 64 + d4);
    float4 sn = *(const float4*)(sinT + lpos * 64 + d4);
    ushort4 o1, o2;
    o1.x = f2bf((bf2f(v1.x) * cs.x - bf2f(v2.x) * sn.x) * sc);
    o1.y = f2bf((bf2f(v1.y) * cs.y - bf2f(v2.y) * sn.y) * sc);
    o1.z = f2bf((bf2f(v1.z) * cs.z - bf2f(v2.z) * sn.z) * sc);
    o1.w = f2bf((bf2f(v1.w) * cs.w - bf2f(v2.w) * sn.w) * sc);
    o2.x = f2bf((bf2f(v2.x) * cs.x + bf2f(v1.x) * sn.x) * sc);
    o2.y = f2bf((bf2f(v2.y) * cs.y + bf2f(v1.y) * sn.y) * sc);
    o2.z = f2bf((bf2f(v2.z) * cs.z + bf2f(v1.z) * sn.z) * sc);
    o2.w = f2bf((bf2f(v2.w) * cs.w + bf2f(v1.w) * sn.w) * sc);
    *(ushort4*)(p + d4)      = o1;
    *(ushort4*)(p + d4 + 64) = o2;
  } else if (bk < 7168) {
    // vT[(b*4+kv)*512 + e][32-group(l) + pi(l&31)] = V[l][e]
    int idx = bk - 5120;                    // 8 e-tiles x 32 l-tiles x 8 bkv
    int ex = idx & 7, ly = (idx >> 3) & 31, bkv = idx >> 8;
    int b = bkv >> 2, kv = bkv & 3;
    int e0 = ex * 64, l0 = ly * 64;
    const u16* src = qkv + (size_t)(b * 2048) * 4608 + 2560 + kv * 512;
    int tc = (t & 15) * 4, tr = t >> 4;     // tr 0..15
#pragma unroll
    for (int i = 0; i < 4; ++i) {
      int lrow = tr + i * 16;
      ushort4 v = *(const ushort4*)(src + (size_t)(l0 + lrow) * 4608 + e0 + tc);
      tile[tc + 0][lrow] = v.x;
      tile[tc + 1][lrow] = v.y;
      tile[tc + 2][lrow] = v.z;
      tile[tc + 3][lrow] = v.w;
    }
    __syncthreads();
    u16* dst = vT + (size_t)(bkv * 512) * 2048;
    const int colb = l0 + ((tc >> 5) & 1) * 32 + ((tc >> 2) & 3) * 8 + ((tc >> 4) & 1) * 4;
#pragma unroll
    for (int i = 0; i < 4; ++i) {
      int er = tr + i * 16;
      ushort4 o;
      o.x = tile[er][tc]; o.y = tile[er][tc + 1];
      o.z = tile[er][tc + 2]; o.w = tile[er][tc + 3];
      *(ushort4*)(dst + (size_t)(e0 + er) * 2048 + colb) = o;
    }
  } else {
    // W_out [8192][2048] -> WobT [2048][8192], 64x64 tiles (32 cx x 128 ry)
    int idx = bk - 7168;
    int c0 = (idx & 31) * 64, r0 = (idx >> 5) * 64;
    int tc = (t & 15) * 4, tr = t >> 4;
#pragma unroll
    for (int i = 0; i < 4; ++i) {
      int r = tr + i * 16;
      float4 v = *(const float4*)(W_out + (size_t)(r0 + r) * 2048 + c0 + tc);
      tile[tc + 0][r] = f2bf(v.x);
      tile[tc + 1][r] = f2bf(v.y);
      tile[tc + 2][r] = f2bf(v.z);
      tile[tc + 3][r] = f2bf(v.w);
    }
    __syncthreads();
#pragma unroll
    for (int i = 0; i < 4; ++i) {
      int cc = tr + i * 16;
      ushort4 o;
      o.x = tile[cc][tc]; o.y = tile[cc][tc + 1];
      o.z = tile[cc][tc + 2]; o.w = tile[cc][tc + 3];
      *(ushort4*)(WobT + (size_t)(c0 + cc) * 8192 + r0 + tc) = o;
    }
  }
}

// ---------------- flash attention v8 (R11-validated): KVBLK=64, shuffle-free ----------------
__global__ __launch_bounds__(512, 2) void attn_kernel(
    const u16* __restrict__ qkv, const u16* __restrict__ vT,
    u16* __restrict__ ctxb) {
  const int wg = blockIdx.x;
  const int pg = wg & 7, qt = wg >> 3;
  const int kvg = pg & 3, b = pg >> 2;
  const int t = threadIdx.x, w = t >> 6, l = t & 63;
  const int lr = l & 15, lg = l >> 4;
  const int h4 = w >> 1, eh = w & 1;
  const int h = kvg * 4 + h4;

  __shared__ __align__(16) u16 lK[2][64 * 128];   // 2 x 16KB
  __shared__ __align__(16) u16 lV[2][512 * 64];   // 2 x 64KB

  f32x4 zero = {0.f, 0.f, 0.f, 0.f};

  bf16x8 qf[2][4];
  const size_t qbase = (size_t)(b * 2048 + qt * 32);
#pragma unroll
  for (int m = 0; m < 2; ++m)
#pragma unroll
    for (int dc = 0; dc < 4; ++dc)
      qf[m][dc] = *(const bf16x8*)(qkv + (qbase + m * 16 + lr) * 4608 + h * 128 + dc * 32 + lg * 8);

  f32x4 acc[2][16];
#pragma unroll
  for (int m = 0; m < 2; ++m)
#pragma unroll
    for (int e = 0; e < 16; ++e) acc[m][e] = zero;
  float m_r[2] = {-1e30f, -1e30f};   // log2-domain running max (per q = lr)
  float l_r[2] = {0.f, 0.f};         // per-lane partial denominators

  const size_t kbase = (size_t)(b * 2048) * 4608 + 2048 + kvg * 128;
  const size_t vbase = (size_t)((b * 4 + kvg) * 512) * 2048;

  const int krow = t >> 4;
  const int kp = t & 15;
  const int ks = (kp & 8) | ((kp ^ (krow & 7)) & 7);
  const u16* ksrc0 = qkv + kbase + (size_t)krow * 4608 + ks * 8;
  const int vs = (t & 7) ^ ((t >> 3) & 7);
  const int ve0 = (t >> 3) * 2 + (vs >> 2);
  const u16* vsrc0 = vT + vbase + (size_t)ve0 * 2048 + (vs & 3) * 8;

  const int vfoff = (eh * 128 + (lr >> 1)) * 128 +
                    (((((lr & 1) << 2) | lg) ^ ((lr >> 1) & 7)) << 4);

  auto stage = [&](int bi, int kv0) {
#pragma unroll
    for (int i = 0; i < 2; ++i)
      glds16(ksrc0 + (size_t)(kv0 + i * 32) * 4608, &lK[bi][i * 4096 + t * 8]);
#pragma unroll
    for (int hh = 0; hh < 2; ++hh)
#pragma unroll
      for (int i = 0; i < 4; ++i)
        glds16(vsrc0 + (kv0 + hh * 32) + (size_t)i * 262144,
               &lV[bi][hh * 16384 + i * 4096 + t * 8]);
  };

  stage(0, 0);

  auto half_body = [&](const char* lKc, const char* lVc) {
    f32x4 sT[2][2];
    sT[0][0] = zero; sT[0][1] = zero; sT[1][0] = zero; sT[1][1] = zero;
    __builtin_amdgcn_s_setprio(1);
#pragma unroll
    for (int dc = 0; dc < 4; ++dc) {
      int slot = dc * 4 + lg;
      int sw = (slot & 8) | ((slot ^ (lr & 7)) & 7);
#pragma unroll
      for (int kt = 0; kt < 2; ++kt) {
        bf16x8 kf = *(const bf16x8*)(lKc + (kt * 16 + lr) * 256 + sw * 16);
        sT[kt][0] = MFMA(kf, qf[0][dc], sT[kt][0]);
        sT[kt][1] = MFMA(kf, qf[1][dc], sT[kt][1]);
      }
    }
    __builtin_amdgcn_s_setprio(0);

    float lmax[2];
#pragma unroll
    for (int m = 0; m < 2; ++m) {
      float a0 = fmaxf(fmaxf(sT[0][m][0], sT[0][m][1]), fmaxf(sT[0][m][2], sT[0][m][3]));
      float a1 = fmaxf(fmaxf(sT[1][m][0], sT[1][m][1]), fmaxf(sT[1][m][2], sT[1][m][3]));
      lmax[m] = fmaxf(a0, a1);
    }
    bool need = (lmax[0] > m_r[0] + 11.5f) || (lmax[1] > m_r[1] + 11.5f);
    if (__any(need)) {                      // rare: reduce, rescale acc & partials
#pragma unroll
      for (int m = 0; m < 2; ++m) {
        float r = lmax[m];
        r = fmaxf(r, __shfl_xor(r, 16));
        r = fmaxf(r, __shfl_xor(r, 32));
        float mn = fmaxf(m_r[m], r);
        float al = ex2(m_r[m] - mn);
        m_r[m] = mn; l_r[m] *= al;
        float alj[4];
#pragma unroll
        for (int j = 0; j < 4; ++j) alj[j] = __shfl(al, lg * 4 + j);
#pragma unroll
        for (int e = 0; e < 16; ++e)
#pragma unroll
          for (int j = 0; j < 4; ++j) acc[m][e][j] *= alj[j];
      }
    }

    bf16x8 pf[2];
#pragma unroll
    for (int m = 0; m < 2; ++m) {
      float p0 = ex2(sT[0][m][0] - m_r[m]), p1 = ex2(sT[0][m][1] - m_r[m]);
      float p2 = ex2(sT[0][m][2] - m_r[m]), p3 = ex2(sT[0][m][3] - m_r[m]);
      float p4 = ex2(sT[1][m][0] - m_r[m]), p5 = ex2(sT[1][m][1] - m_r[m]);
      float p6 = ex2(sT[1][m][2] - m_r[m]), p7 = ex2(sT[1][m][3] - m_r[m]);
      l_r[m] += ((p0 + p1) + (p2 + p3)) + ((p4 + p5) + (p6 + p7));
      union { bf16x8 v; unsigned wd[4]; } u;
      u.wd[0] = cvt_pk_bf16(p0, p1);
      u.wd[1] = cvt_pk_bf16(p2, p3);
      u.wd[2] = cvt_pk_bf16(p4, p5);
      u.wd[3] = cvt_pk_bf16(p6, p7);
      pf[m] = u.v;
    }

    __builtin_amdgcn_s_setprio(1);
#pragma unroll
    for (int e = 0; e < 16; ++e) {
      bf16x8 vf = *(const bf16x8*)(lVc + vfoff + e * 1024);
      acc[0][e] = MFMA(pf[0], vf, acc[0][e]);
      acc[1][e] = MFMA(pf[1], vf, acc[1][e]);
    }
    __builtin_amdgcn_s_setprio(0);
  };

  for (int it = 0; it < 32; ++it) {
    const int cur = it & 1;
    __syncthreads();                         // certify tile(it); drains all reads
    if (it + 1 < 32) stage(cur ^ 1, 64 * (it + 1));
    const char* lKc = (const char*)lK[cur];
    const char* lVc = (const char*)lV[cur];
    half_body(lKc, lVc);                     // kv [64it, 64it+32)
    half_body(lKc + 8192, lVc + 32768);      // kv [64it+32, 64it+64)
  }

  // ---- epilogue: deferred l_r reduction, then normalize & store ----
#pragma unroll
  for (int m = 0; m < 2; ++m) {
    float s = l_r[m];
    s += __shfl_xor(s, 16);
    s += __shfl_xor(s, 32);
    l_r[m] = s;
  }
#pragma unroll
  for (int m = 0; m < 2; ++m) {
    float linv[4];
#pragma unroll
    for (int j = 0; j < 4; ++j) linv[j] = 1.0f / __shfl(l_r[m], lg * 4 + j);
    const size_t orow0 = qbase + m * 16 + lg * 4;
#pragma unroll
    for (int e = 0; e < 16; ++e)
#pragma unroll
      for (int j = 0; j < 4; ++j)
        ctxb[(orow0 + j) * 8192 + h * 512 + eh * 256 + e * 16 + lr] =
            f2bf(acc[m][e][j] * linv[j]);
  }
}

// ---------------- launch ----------------
extern "C" void kernel_launch(void* const* d_in, const int* in_sizes, int n_in,
                              void* d_out, int out_size, void* d_ws, size_t ws_size,
                              hipStream_t stream) {
  const float* x      = (const float*)d_in[0];
  const float* W_attn = (const float*)d_in[1];
  const float* W_out  = (const float*)d_in[2];
  const float* b_out  = (const float*)d_in[3];
  float* out = (float*)d_out;
  char* ws = (char*)d_ws;

  if (ws_size < 158334976u) return;  // need ~151MB scratch

  float* sinT = (float*)(ws + 0);
  float* cosT = (float*)(ws + 524288);
  u16* xb   = (u16*)(ws + 1048576);    // 16MB   (dead after GEMM1)
  u16* WbT  = (u16*)(ws + 17825792);   // 18MB   (dead after GEMM1)
  u16* qkvb = (u16*)(ws + 36700160);   // 36MB
  u16* vT   = (u16*)(ws + 74448896);   // 16MB
  u16* ctxb = (u16*)(ws + 91226112);   // 64MB
  u16* WobT = (u16*)(ws + 1048576);    // 32MB, reuses xb+WbT region post-GEMM1

  prep_kernel<<<11008, 256, 0, stream>>>(x, W_attn, sinT, cosT, xb, WbT);
  gemm1_8ph<<<288, 512, 0, stream>>>(xb, WbT, qkvb);
  ropevt_kernel<<<11264, 256, 0, stream>>>(qkvb, sinT, cosT, vT, W_out, WobT);
  attn_kernel<<<512, 512, 0, stream>>>(qkvb, vT, ctxb);
  gemm_4ph<1, 8192, 2048><<<256, 512, 0, stream>>>(ctxb, WobT, nullptr, out, b_out);
}

// Round 19
// 547.600 us; speedup vs baseline: 1.0050x; 1.0011x over previous
//
#include <hip/hip_runtime.h>

typedef unsigned short u16;
typedef float f32x4 __attribute__((ext_vector_type(4)));
typedef __bf16 bf16x8 __attribute__((ext_vector_type(8)));

#define DEV static __device__ __forceinline__

DEV u16 f2bf(float f) {
  union { float f; unsigned u; } c; c.f = f;
  unsigned u = c.u;
  u += 0x7fffu + ((u >> 16) & 1u);   // RNE; inputs are normal floats
  return (u16)(u >> 16);
}
DEV float bf2f(u16 h) {
  union { float f; unsigned u; } c; c.u = ((unsigned)h) << 16;
  return c.f;
}
DEV f32x4 MFMA(bf16x8 a, bf16x8 b, f32x4 c) {
  return __builtin_amdgcn_mfma_f32_16x16x32_bf16(a, b, c, 0, 0, 0);
}
DEV unsigned cvt_pk_bf16(float a, float b) {   // low16 = a, high16 = b (RNE)
  unsigned r;
  asm("v_cvt_pk_bf16_f32 %0, %1, %2" : "=v"(r) : "v"(a), "v"(b));
  return r;
}
DEV float ex2(float x) { return __builtin_amdgcn_exp2f(x); }
DEV void glds16(const void* src, void* lds) {   // async global->LDS, 16B/lane
  __builtin_amdgcn_global_load_lds(
      (__attribute__((address_space(1))) void*)src,
      (__attribute__((address_space(3))) void*)lds, 16, 0, 0);
}
DEV void barrier_raw() {                        // raw s_barrier: NO vmcnt drain
  __builtin_amdgcn_sched_barrier(0);
  asm volatile("s_barrier" ::: "memory");
  __builtin_amdgcn_sched_barrier(0);
}
#define VMCNT(N)                                              \
  do {                                                        \
    asm volatile("s_waitcnt vmcnt(" #N ")" ::: "memory");     \
    __builtin_amdgcn_sched_barrier(0);                        \
  } while (0)

// ---------------- constants ----------------
// B=2 L=2048 DM=2048 H=16 KV=4 GROUP=4 DK=128 DV=512
// qkv row layout: [0,2048) q (16x128) | [2048,2560) k (4x128) | [2560,4608) v (4x512)

// ---------------- fused prep: rope tables + x cast + W_attn transpose (64x64) ----------------
// grid 11008 x 256: [0,512) tables | [512,8704) cast | [8704,11008) transposeA 64x64
__global__ void prep_kernel(const float* __restrict__ x, const float* __restrict__ W_attn,
                            float* __restrict__ sinT, float* __restrict__ cosT,
                            u16* __restrict__ xb, u16* __restrict__ WbT) {
  __shared__ u16 tile[64][72];   // stride 144B: 8B-aligned rows
  const int bk = blockIdx.x, t = threadIdx.x;
  if (bk < 512) {
    int idx = bk * 256 + t;                 // 2048*64
    int l = idx >> 6, i = idx & 63;
    float inv = __expf(-((float)(2 * i) / 128.0f) * 9.210340371976184f);
    float ang = (float)l * inv;
    sinT[idx] = sinf(ang);
    cosT[idx] = cosf(ang);
  } else if (bk < 8704) {
    int i = ((bk - 512) * 256 + t) * 4;
    float4 v = *(const float4*)(x + i);
    ushort4 o;
    o.x = f2bf(v.x); o.y = f2bf(v.y); o.z = f2bf(v.z); o.w = f2bf(v.w);
    *(ushort4*)(xb + i) = o;
  } else {
    // W_attn [2048][4608] -> WbT [4608][2048], 64x64 tiles, float4 in / ushort4 out
    int idx = bk - 8704;                    // 72 x 32 tiles
    int c0 = (idx % 72) * 64, r0 = (idx / 72) * 64;
    int tc = (t & 15) * 4, tr = t >> 4;     // tr 0..15
#pragma unroll
    for (int i = 0; i < 4; ++i) {
      int r = tr + i * 16;
      float4 v = *(const float4*)(W_attn + (size_t)(r0 + r) * 4608 + c0 + tc);
      tile[tc + 0][r] = f2bf(v.x);
      tile[tc + 1][r] = f2bf(v.y);
      tile[tc + 2][r] = f2bf(v.z);
      tile[tc + 3][r] = f2bf(v.w);
    }
    __syncthreads();
#pragma unroll
    for (int i = 0; i < 4; ++i) {
      int cc = tr + i * 16;
      ushort4 o;
      o.x = tile[cc][tc]; o.y = tile[cc][tc + 1];
      o.z = tile[cc][tc + 2]; o.w = tile[cc][tc + 3];
      *(ushort4*)(WbT + (size_t)(c0 + cc) * 2048 + r0 + tc) = o;
    }
  }
}

// ================= GEMM1: qkv = xb @ WbT^T ================= (R11-validated, 8-phase 256^2)
__global__ __launch_bounds__(512) void gemm1_8ph(const u16* __restrict__ A,
                                                 const u16* __restrict__ Bt,
                                                 u16* __restrict__ C) {
  constexpr int K = 2048, N = 4608, NT = 32;   // NT = K/64
  __shared__ __align__(16) u16 lA[2][2][8192];
  __shared__ __align__(16) u16 lB[2][2][8192];
  const int t = threadIdx.x, w = t >> 6, l = t & 63;
  const int lr = l & 15, lg = l >> 4;
  const int wr = w >> 2, wn = w & 3;
  const int swz = (blockIdx.x & 7) * 36 + (blockIdx.x >> 3);  // 288 blocks, XCD-chunked
  const int bm = swz & 15, bn = swz >> 4;                      // 16 x 18

  const size_t aBase = (size_t)(bm * 256) * K;
  const size_t bBase = (size_t)(bn * 256) * K;
  const int lslog = (t & 3) ^ ((t >> 3) & 3);     // staging: logical slot for linear dest
  const int r128 = t >> 2;
  const int aswz = (lg ^ ((lr >> 1) & 3)) << 4;   // frag-read physical slot byte offset

  auto stA = [&](int buf, int kk, int tile) {
#pragma unroll
    for (int i = 0; i < 2; ++i) {
      int row = i * 128 + r128;
      glds16(A + aBase + (size_t)row * K + tile * 64 + kk * 32 + lslog * 8,
             &lA[buf][kk][i * 4096 + t * 8]);
    }
  };
  auto stB = [&](int buf, int kk, int tile) {
#pragma unroll
    for (int i = 0; i < 2; ++i) {
      int row = i * 128 + r128;
      glds16(Bt + bBase + (size_t)row * K + tile * 64 + kk * 32 + lslog * 8,
             &lB[buf][kk][i * 4096 + t * 8]);
    }
  };

  f32x4 acc[8][4];
#pragma unroll
  for (int f = 0; f < 8; ++f)
#pragma unroll
    for (int g = 0; g < 4; ++g) acc[f][g] = f32x4{0.f, 0.f, 0.f, 0.f};

  // prologue: 12 loads out; vmcnt(8) completes (0,0,t0); barrier certifies it.
  stA(0, 0, 0); stB(0, 0, 0); stA(0, 1, 0); stB(0, 1, 0); stA(1, 0, 1); stB(1, 0, 1);
  VMCNT(8);
  barrier_raw();

  auto PH = [&](int buf, int kk, int mh, auto&& st) {
    bf16x8 af[4], bb[4];
    const char* pA = (const char*)lA[buf][kk];
    const char* pB = (const char*)lB[buf][kk];
#pragma unroll
    for (int f = 0; f < 4; ++f) {
      af[f] = *(const bf16x8*)(pA + (wr * 128 + (mh * 4 + f) * 16 + lr) * 64 + aswz);
      bb[f] = *(const bf16x8*)(pB + (wn * 64 + f * 16 + lr) * 64 + aswz);
    }
    st();
    __builtin_amdgcn_s_setprio(1);
#pragma unroll
    for (int f = 0; f < 4; ++f)
#pragma unroll
      for (int g = 0; g < 4; ++g)
        acc[mh * 4 + f][g] = MFMA(af[f], bb[g], acc[mh * 4 + f][g]);
    __builtin_amdgcn_s_setprio(0);
  };
  auto NOST = [] {};

  for (int i = 0; i < NT / 2 - 1; ++i) {
    const int t1 = 2 * i + 1, t2 = 2 * i + 2, t3 = 2 * i + 3;
    PH(0, 0, 0, [&] { stA(1, 1, t1); });            barrier_raw();
    PH(0, 0, 1, [&] { stB(1, 1, t1); }); VMCNT(8);  barrier_raw();
    PH(0, 1, 0, [&] { stA(0, 0, t2); });            barrier_raw();
    PH(0, 1, 1, [&] { stB(0, 0, t2); }); VMCNT(8);  barrier_raw();
    PH(1, 0, 0, [&] { stA(0, 1, t2); });            barrier_raw();
    PH(1, 0, 1, [&] { stB(0, 1, t2); }); VMCNT(8);  barrier_raw();
    PH(1, 1, 0, [&] { stA(1, 0, t3); });            barrier_raw();
    PH(1, 1, 1, [&] { stB(1, 0, t3); }); VMCNT(8);  barrier_raw();
  }
  // peel: tiles NT-2 (buf0, certified), NT-1 (buf1). Waits drain 8 -> 4 -> 0.
  PH(0, 0, 0, [&] { stA(1, 1, NT - 1); });           barrier_raw();
  PH(0, 0, 1, [&] { stB(1, 1, NT - 1); }); VMCNT(8); barrier_raw();
  PH(0, 1, 0, NOST);                                 barrier_raw();
  PH(0, 1, 1, NOST);                       VMCNT(4); barrier_raw();
  PH(1, 0, 0, NOST);                                 barrier_raw();
  PH(1, 0, 1, NOST);                       VMCNT(0); barrier_raw();
  PH(1, 1, 0, NOST);                                 barrier_raw();
  PH(1, 1, 1, NOST);

  const int crow0 = bm * 256 + wr * 128;
  const int ccol0 = bn * 256 + wn * 64;
#pragma unroll
  for (int f = 0; f < 8; ++f)
#pragma unroll
    for (int g = 0; g < 4; ++g)
#pragma unroll
      for (int j = 0; j < 4; ++j)
        C[(size_t)(crow0 + f * 16 + lg * 4 + j) * N + ccol0 + g * 16 + lr] =
            f2bf(acc[f][g][j]);
}

// ================= GEMM2: out = ctxb @ WobT^T + bias ================= (R6-validated)
template <int WRITE_F32, int K, int N>
__global__ __launch_bounds__(512) void gemm_4ph(const u16* __restrict__ A,
                                                const u16* __restrict__ Bt,
                                                u16* __restrict__ Cb,
                                                float* __restrict__ Cf,
                                                const float* __restrict__ bias) {
  constexpr int NT = K / 64;
  constexpr int NBN = N / 128;
  __shared__ __align__(16) u16 lA[2][2][8192];   // 64KB
  __shared__ __align__(16) u16 lB[2][2][4096];   // 32KB
  const int t = threadIdx.x, w = t >> 6, l = t & 63;
  const int lr = l & 15, lg = l >> 4;
  const int wr = w >> 1, wn = w & 1;
  const int swz = (blockIdx.x & 7) * (2 * NBN) + (blockIdx.x >> 3);  // 16*NBN blocks
  const int bm = swz & 15, bn = swz >> 4;

  const size_t aBase = (size_t)(bm * 256) * K;
  const size_t bBase = (size_t)(bn * 128) * K;
  const int lslog = (t & 3) ^ ((t >> 3) & 3);
  const int r128 = t >> 2;
  const int aswz = (lg ^ ((lr >> 1) & 3)) << 4;

  auto stA = [&](int buf, int kk, int tile) {
#pragma unroll
    for (int i = 0; i < 2; ++i) {
      int row = i * 128 + r128;
      glds16(A + aBase + (size_t)row * K + tile * 64 + kk * 32 + lslog * 8,
             &lA[buf][kk][i * 4096 + t * 8]);
    }
  };
  auto stB = [&](int buf, int kk, int tile) {
    glds16(Bt + bBase + (size_t)r128 * K + tile * 64 + kk * 32 + lslog * 8,
           &lB[buf][kk][t * 8]);
  };

  f32x4 acc[4][4];
#pragma unroll
  for (int f = 0; f < 4; ++f)
#pragma unroll
    for (int g = 0; g < 4; ++g) acc[f][g] = f32x4{0.f, 0.f, 0.f, 0.f};

  // prologue: 9 loads; vmcnt(6) completes (0,0,t0); barrier certifies.
  stA(0, 0, 0); stB(0, 0, 0); stA(0, 1, 0); stB(0, 1, 0); stA(1, 0, 1); stB(1, 0, 1);
  VMCNT(6);
  barrier_raw();

  auto PH = [&](int buf, int kk, auto&& st) {
    bf16x8 af[4], bb[4];
    const char* pA = (const char*)lA[buf][kk];
    const char* pB = (const char*)lB[buf][kk];
#pragma unroll
    for (int f = 0; f < 4; ++f) {
      af[f] = *(const bf16x8*)(pA + (wr * 64 + f * 16 + lr) * 64 + aswz);
      bb[f] = *(const bf16x8*)(pB + (wn * 64 + f * 16 + lr) * 64 + aswz);
    }
    st();
    __builtin_amdgcn_s_setprio(1);
#pragma unroll
    for (int f = 0; f < 4; ++f)
#pragma unroll
      for (int g = 0; g < 4; ++g)
        acc[f][g] = MFMA(af[f], bb[g], acc[f][g]);
    __builtin_amdgcn_s_setprio(0);
  };
  auto NOST = [] {};

  for (int i = 0; i < NT / 2 - 1; ++i) {
    const int t1 = 2 * i + 1, t2 = 2 * i + 2, t3 = 2 * i + 3;
    PH(0, 0, [&] { stA(1, 1, t1); stB(1, 1, t1); }); VMCNT(6); barrier_raw();
    PH(0, 1, [&] { stA(0, 0, t2); stB(0, 0, t2); }); VMCNT(6); barrier_raw();
    PH(1, 0, [&] { stA(0, 1, t2); stB(0, 1, t2); }); VMCNT(6); barrier_raw();
    PH(1, 1, [&] { stA(1, 0, t3); stB(1, 0, t3); }); VMCNT(6); barrier_raw();
  }
  // peel: tiles NT-2 (buf0, certified), NT-1 (buf1). Waits 6 -> 3 -> 0.
  PH(0, 0, [&] { stA(1, 1, NT - 1); stB(1, 1, NT - 1); }); VMCNT(6); barrier_raw();
  PH(0, 1, NOST);                                          VMCNT(3); barrier_raw();
  PH(1, 0, NOST);                                          VMCNT(0); barrier_raw();
  PH(1, 1, NOST);

  const int crow0 = bm * 256 + wr * 64;
  const int ccol0 = bn * 128 + wn * 64;
#pragma unroll
  for (int g = 0; g < 4; ++g) {
    float bv = WRITE_F32 ? bias[ccol0 + g * 16 + lr] : 0.f;
#pragma unroll
    for (int f = 0; f < 4; ++f)
#pragma unroll
      for (int j = 0; j < 4; ++j) {
        size_t off = (size_t)(crow0 + f * 16 + lg * 4 + j) * N + ccol0 + g * 16 + lr;
        if (WRITE_F32) Cf[off] = acc[f][g][j] + bv;
        else           Cb[off] = f2bf(acc[f][g][j]);
      }
  }
}

// ---------------- fused rope + V^T + W_out transpose (all post-gemm1, pre-gemm2) ----------------
// grid 11264 x 256: [0,5120) rope x4-wide | [5120,7168) vt 64x64 | [7168,11264) transposeW 64x64
// rope: thread handles 4 consecutive d; vt: pi identity on low 2 bits -> ushort4 ok.
// transposeW: W_out [8192][2048] -> WobT [2048][8192]; WobT aliases xb/WbT (dead post-gemm1).
__global__ void ropevt_kernel(u16* __restrict__ qkv, const float* __restrict__ sinT,
                              const float* __restrict__ cosT, u16* __restrict__ vT,
                              const float* __restrict__ W_out, u16* __restrict__ WobT) {
  __shared__ u16 tile[64][72];
  const int bk = blockIdx.x, t = threadIdx.x;
  if (bk < 5120) {
    int idx = bk * 256 + t;                 // 4096 rows * 20 heads * 16 (x4 d)
    int d4 = (idx & 15) * 4;
    int rh = idx >> 4;
    int head = rh % 20;
    int row = rh / 20;
    int lpos = row & 2047;
    int col = head < 16 ? head * 128 : 2048 + (head - 16) * 128;
    float sc = head < 16 ? 0.12751743561938476f : 1.0f;   // log2e/sqrt(128) into Q
    u16* p = qkv + (size_t)row * 4608 + col;
    ushort4 v1 = *(const ushort4*)(p + d4);
    ushort4 v2 = *(const ushort4*)(p + d4 + 64);
    float4 cs = *(const float4*)(cosT + lpos * 64 + d4);
    float4 sn = *(const float4*)(sinT + lpos * 64 + d4);
    ushort4 o1, o2;
    o1.x = f2bf((bf2f(v1.x) * cs.x - bf2f(v2.x) * sn.x) * sc);
    o1.y = f2bf((bf2f(v1.y) * cs.y - bf2f(v2.y) * sn.y) * sc);
    o1.z = f2bf((bf2f(v1.z) * cs.z - bf2f(v2.z) * sn.z) * sc);
    o1.w = f2bf((bf2f(v1.w) * cs.w - bf2f(v2.w) * sn.w) * sc);
    o2.x = f2bf((bf2f(v2.x) * cs.x + bf2f(v1.x) * sn.x) * sc);
    o2.y = f2bf((bf2f(v2.y) * cs.y + bf2f(v1.y) * sn.y) * sc);
    o2.z = f2bf((bf2f(v2.z) * cs.z + bf2f(v1.z) * sn.z) * sc);
    o2.w = f2bf((bf2f(v2.w) * cs.w + bf2f(v1.w) * sn.w) * sc);
    *(ushort4*)(p + d4)      = o1;
    *(ushort4*)(p + d4 + 64) = o2;
  } else if (bk < 7168) {
    // vT[(b*4+kv)*512 + e][32-group(l) + pi(l&31)] = V[l][e]
    int idx = bk - 5120;                    // 8 e-tiles x 32 l-tiles x 8 bkv
    int ex = idx & 7, ly = (idx >> 3) & 31, bkv = idx >> 8;
    int b = bkv >> 2, kv = bkv & 3;
    int e0 = ex * 64, l0 = ly * 64;
    const u16* src = qkv + (size_t)(b * 2048) * 4608 + 2560 + kv * 512;
    int tc = (t & 15) * 4, tr = t >> 4;     // tr 0..15
#pragma unroll
    for (int i = 0; i < 4; ++i) {
      int lrow = tr + i * 16;
      ushort4 v = *(const ushort4*)(src + (size_t)(l0 + lrow) * 4608 + e0 + tc);
      tile[tc + 0][lrow] = v.x;
      tile[tc + 1][lrow] = v.y;
      tile[tc + 2][lrow] = v.z;
      tile[tc + 3][lrow] = v.w;
    }
    __syncthreads();
    u16* dst = vT + (size_t)(bkv * 512) * 2048;
    const int colb = l0 + ((tc >> 5) & 1) * 32 + ((tc >> 2) & 3) * 8 + ((tc >> 4) & 1) * 4;
#pragma unroll
    for (int i = 0; i < 4; ++i) {
      int er = tr + i * 16;
      ushort4 o;
      o.x = tile[er][tc]; o.y = tile[er][tc + 1];
      o.z = tile[er][tc + 2]; o.w = tile[er][tc + 3];
      *(ushort4*)(dst + (size_t)(e0 + er) * 2048 + colb) = o;
    }
  } else {
    // W_out [8192][2048] -> WobT [2048][8192], 64x64 tiles (32 cx x 128 ry)
    int idx = bk - 7168;
    int c0 = (idx & 31) * 64, r0 = (idx >> 5) * 64;
    int tc = (t & 15) * 4, tr = t >> 4;
#pragma unroll
    for (int i = 0; i < 4; ++i) {
      int r = tr + i * 16;
      float4 v = *(const float4*)(W_out + (size_t)(r0 + r) * 2048 + c0 + tc);
      tile[tc + 0][r] = f2bf(v.x);
      tile[tc + 1][r] = f2bf(v.y);
      tile[tc + 2][r] = f2bf(v.z);
      tile[tc + 3][r] = f2bf(v.w);
    }
    __syncthreads();
#pragma unroll
    for (int i = 0; i < 4; ++i) {
      int cc = tr + i * 16;
      ushort4 o;
      o.x = tile[cc][tc]; o.y = tile[cc][tc + 1];
      o.z = tile[cc][tc + 2]; o.w = tile[cc][tc + 3];
      *(ushort4*)(WobT + (size_t)(c0 + cc) * 8192 + r0 + tc) = o;
    }
  }
}

// ---------------- flash attention v8 (R11-validated): KVBLK=64, shuffle-free ----------------
__global__ __launch_bounds__(512, 2) void attn_kernel(
    const u16* __restrict__ qkv, const u16* __restrict__ vT,
    u16* __restrict__ ctxb) {
  const int wg = blockIdx.x;
  const int pg = wg & 7, qt = wg >> 3;
  const int kvg = pg & 3, b = pg >> 2;
  const int t = threadIdx.x, w = t >> 6, l = t & 63;
  const int lr = l & 15, lg = l >> 4;
  const int h4 = w >> 1, eh = w & 1;
  const int h = kvg * 4 + h4;

  __shared__ __align__(16) u16 lK[2][64 * 128];   // 2 x 16KB
  __shared__ __align__(16) u16 lV[2][512 * 64];   // 2 x 64KB

  f32x4 zero = {0.f, 0.f, 0.f, 0.f};

  bf16x8 qf[2][4];
  const size_t qbase = (size_t)(b * 2048 + qt * 32);
#pragma unroll
  for (int m = 0; m < 2; ++m)
#pragma unroll
    for (int dc = 0; dc < 4; ++dc)
      qf[m][dc] = *(const bf16x8*)(qkv + (qbase + m * 16 + lr) * 4608 + h * 128 + dc * 32 + lg * 8);

  f32x4 acc[2][16];
#pragma unroll
  for (int m = 0; m < 2; ++m)
#pragma unroll
    for (int e = 0; e < 16; ++e) acc[m][e] = zero;
  float m_r[2] = {-1e30f, -1e30f};   // log2-domain running max (per q = lr)
  float l_r[2] = {0.f, 0.f};         // per-lane partial denominators

  const size_t kbase = (size_t)(b * 2048) * 4608 + 2048 + kvg * 128;
  const size_t vbase = (size_t)((b * 4 + kvg) * 512) * 2048;

  const int krow = t >> 4;
  const int kp = t & 15;
  const int ks = (kp & 8) | ((kp ^ (krow & 7)) & 7);
  const u16* ksrc0 = qkv + kbase + (size_t)krow * 4608 + ks * 8;
  const int vs = (t & 7) ^ ((t >> 3) & 7);
  const int ve0 = (t >> 3) * 2 + (vs >> 2);
  const u16* vsrc0 = vT + vbase + (size_t)ve0 * 2048 + (vs & 3) * 8;

  const int vfoff = (eh * 128 + (lr >> 1)) * 128 +
                    (((((lr & 1) << 2) | lg) ^ ((lr >> 1) & 7)) << 4);

  auto stage = [&](int bi, int kv0) {
#pragma unroll
    for (int i = 0; i < 2; ++i)
      glds16(ksrc0 + (size_t)(kv0 + i * 32) * 4608, &lK[bi][i * 4096 + t * 8]);
#pragma unroll
    for (int hh = 0; hh < 2; ++hh)
#pragma unroll
      for (int i = 0; i < 4; ++i)
        glds16(vsrc0 + (kv0 + hh * 32) + (size_t)i * 262144,
               &lV[bi][hh * 16384 + i * 4096 + t * 8]);
  };

  stage(0, 0);

  auto half_body = [&](const char* lKc, const char* lVc) {
    f32x4 sT[2][2];
    sT[0][0] = zero; sT[0][1] = zero; sT[1][0] = zero; sT[1][1] = zero;
    __builtin_amdgcn_s_setprio(1);
#pragma unroll
    for (int dc = 0; dc < 4; ++dc) {
      int slot = dc * 4 + lg;
      int sw = (slot & 8) | ((slot ^ (lr & 7)) & 7);
#pragma unroll
      for (int kt = 0; kt < 2; ++kt) {
        bf16x8 kf = *(const bf16x8*)(lKc + (kt * 16 + lr) * 256 + sw * 16);
        sT[kt][0] = MFMA(kf, qf[0][dc], sT[kt][0]);
        sT[kt][1] = MFMA(kf, qf[1][dc], sT[kt][1]);
      }
    }
    __builtin_amdgcn_s_setprio(0);

    float lmax[2];
#pragma unroll
    for (int m = 0; m < 2; ++m) {
      float a0 = fmaxf(fmaxf(sT[0][m][0], sT[0][m][1]), fmaxf(sT[0][m][2], sT[0][m][3]));
      float a1 = fmaxf(fmaxf(sT[1][m][0], sT[1][m][1]), fmaxf(sT[1][m][2], sT[1][m][3]));
      lmax[m] = fmaxf(a0, a1);
    }
    bool need = (lmax[0] > m_r[0] + 11.5f) || (lmax[1] > m_r[1] + 11.5f);
    if (__any(need)) {                      // rare: reduce, rescale acc & partials
#pragma unroll
      for (int m = 0; m < 2; ++m) {
        float r = lmax[m];
        r = fmaxf(r, __shfl_xor(r, 16));
        r = fmaxf(r, __shfl_xor(r, 32));
        float mn = fmaxf(m_r[m], r);
        float al = ex2(m_r[m] - mn);
        m_r[m] = mn; l_r[m] *= al;
        float alj[4];
#pragma unroll
        for (int j = 0; j < 4; ++j) alj[j] = __shfl(al, lg * 4 + j);
#pragma unroll
        for (int e = 0; e < 16; ++e)
#pragma unroll
          for (int j = 0; j < 4; ++j) acc[m][e][j] *= alj[j];
      }
    }

    bf16x8 pf[2];
#pragma unroll
    for (int m = 0; m < 2; ++m) {
      float p0 = ex2(sT[0][m][0] - m_r[m]), p1 = ex2(sT[0][m][1] - m_r[m]);
      float p2 = ex2(sT[0][m][2] - m_r[m]), p3 = ex2(sT[0][m][3] - m_r[m]);
      float p4 = ex2(sT[1][m][0] - m_r[m]), p5 = ex2(sT[1][m][1] - m_r[m]);
      float p6 = ex2(sT[1][m][2] - m_r[m]), p7 = ex2(sT[1][m][3] - m_r[m]);
      l_r[m] += ((p0 + p1) + (p2 + p3)) + ((p4 + p5) + (p6 + p7));
      union { bf16x8 v; unsigned wd[4]; } u;
      u.wd[0] = cvt_pk_bf16(p0, p1);
      u.wd[1] = cvt_pk_bf16(p2, p3);
      u.wd[2] = cvt_pk_bf16(p4, p5);
      u.wd[3] = cvt_pk_bf16(p6, p7);
      pf[m] = u.v;
    }

    __builtin_amdgcn_s_setprio(1);
#pragma unroll
    for (int e = 0; e < 16; ++e) {
      bf16x8 vf = *(const bf16x8*)(lVc + vfoff + e * 1024);
      acc[0][e] = MFMA(pf[0], vf, acc[0][e]);
      acc[1][e] = MFMA(pf[1], vf, acc[1][e]);
    }
    __builtin_amdgcn_s_setprio(0);
  };

  for (int it = 0; it < 32; ++it) {
    const int cur = it & 1;
    __syncthreads();                         // certify tile(it); drains all reads
    if (it + 1 < 32) stage(cur ^ 1, 64 * (it + 1));
    const char* lKc = (const char*)lK[cur];
    const char* lVc = (const char*)lV[cur];
    half_body(lKc, lVc);                     // kv [64it, 64it+32)
    half_body(lKc + 8192, lVc + 32768);      // kv [64it+32, 64it+64)
  }

  // ---- epilogue: deferred l_r reduction, then normalize & store ----
#pragma unroll
  for (int m = 0; m < 2; ++m) {
    float s = l_r[m];
    s += __shfl_xor(s, 16);
    s += __shfl_xor(s, 32);
    l_r[m] = s;
  }
#pragma unroll
  for (int m = 0; m < 2; ++m) {
    float linv[4];
#pragma unroll
    for (int j = 0; j < 4; ++j) linv[j] = 1.0f / __shfl(l_r[m], lg * 4 + j);
    const size_t orow0 = qbase + m * 16 + lg * 4;
#pragma unroll
    for (int e = 0; e < 16; ++e)
#pragma unroll
      for (int j = 0; j < 4; ++j)
        ctxb[(orow0 + j) * 8192 + h * 512 + eh * 256 + e * 16 + lr] =
            f2bf(acc[m][e][j] * linv[j]);
  }
}

// ---------------- launch ----------------
extern "C" void kernel_launch(void* const* d_in, const int* in_sizes, int n_in,
                              void* d_out, int out_size, void* d_ws, size_t ws_size,
                              hipStream_t stream) {
  const float* x      = (const float*)d_in[0];
  const float* W_attn = (const float*)d_in[1];
  const float* W_out  = (const float*)d_in[2];
  const float* b_out  = (const float*)d_in[3];
  float* out = (float*)d_out;
  char* ws = (char*)d_ws;

  if (ws_size < 158334976u) return;  // need ~151MB scratch

  float* sinT = (float*)(ws + 0);
  float* cosT = (float*)(ws + 524288);
  u16* xb   = (u16*)(ws + 1048576);    // 16MB   (dead after GEMM1)
  u16* WbT  = (u16*)(ws + 17825792);   // 18MB   (dead after GEMM1)
  u16* qkvb = (u16*)(ws + 36700160);   // 36MB
  u16* vT   = (u16*)(ws + 74448896);   // 16MB
  u16* ctxb = (u16*)(ws + 91226112);   // 64MB
  u16* WobT = (u16*)(ws + 1048576);    // 32MB, reuses xb+WbT region post-GEMM1

  prep_kernel<<<11008, 256, 0, stream>>>(x, W_attn, sinT, cosT, xb, WbT);
  gemm1_8ph<<<288, 512, 0, stream>>>(xb, WbT, qkvb);
  ropevt_kernel<<<11264, 256, 0, stream>>>(qkvb, sinT, cosT, vT, W_out, WobT);
  attn_kernel<<<512, 512, 0, stream>>>(qkvb, vT, ctxb);
  gemm_4ph<1, 8192, 2048><<<256, 512, 0, stream>>>(ctxb, WobT, nullptr, out, b_out);
}